// Round 24
// baseline (194.840 us; speedup 1.0000x reference)
//
#include <hip/hip_runtime.h>
#include <hip/hip_bf16.h>

#define IN_DIM 256
#define HC     64    // H*C for layer 1
#define OUT_DIM 40
#define NEG    0.2f

#define NB_SH   8     // 256 nodes per bucket
#define NB_MASK 255
#define SRC_BITS 17   // n=100000 < 2^17
#define SRC_MASK 0x1FFFF
#define CHUNK   8192  // edges per scatter block
#define LEN_CAP 6144  // place2 LDS capacity (mean bucket len ~4450)

typedef __bf16 bf16x8 __attribute__((ext_vector_type(8)));
typedef float  f32x4  __attribute__((ext_vector_type(4)));

__device__ inline float lrelu(float v) { return fmaxf(v, NEG * v); }  // NEG<1

// ---------------- gemm1 body (512 threads, 128 rows/block, 32KB W in smem) ----------------
__device__ __forceinline__ void gemm1_body(
    char* smem, int tile,
    const float* __restrict__ x, const __bf16* __restrict__ Wt,
    const float* __restrict__ a_s, const float* __restrict__ a_d,
    __bf16* __restrict__ xp1b, float* __restrict__ es1, float* __restrict__ ed1, int n) {
  uint4* wl = (uint4*)smem;   // 32 KB, swizzled 16B units
  int tid = threadIdx.x;
  const uint4* gw = (const uint4*)Wt;
  #pragma unroll
  for (int it = 0; it < 4; ++it) {
    int c16 = it * 512 + tid;
    int row = c16 >> 5;
    int swz = c16 ^ (row & 7);
    wl[swz] = gw[c16];
  }
  __syncthreads();

  int wave = tid >> 6, lane = tid & 63;
  int l15 = lane & 15, kgrp = lane >> 4;
  int rowA = tile * 128 + wave * 16 + l15;
  bool okA = rowA < n;
  const float* xrow = x + (size_t)(okA ? rowA : (n - 1)) * IN_DIM;

  f32x4 va[8][2];
  #pragma unroll
  for (int c = 0; c < 8; ++c) {
    int k0 = c * 32 + kgrp * 8;
    va[c][0] = *(const f32x4*)(xrow + k0);
    va[c][1] = *(const f32x4*)(xrow + k0 + 4);
  }
  __builtin_amdgcn_sched_barrier(0);

  f32x4 acc[4] = {};
  #pragma unroll
  for (int c = 0; c < 8; ++c) {
    bf16x8 ahi, alo;
    #pragma unroll
    for (int i = 0; i < 4; ++i) {
      float f0 = va[c][0][i], f1 = va[c][1][i];
      __bf16 h0 = (__bf16)f0, h1 = (__bf16)f1;
      ahi[i]     = h0;
      ahi[4 + i] = h1;
      alo[i]     = (__bf16)(f0 - (float)h0);
      alo[4 + i] = (__bf16)(f1 - (float)h1);
    }
    #pragma unroll
    for (int t = 0; t < 4; ++t) {
      int row  = t * 16 + l15;
      int unit = row * 32 + c * 4 + kgrp;
      int swz  = unit ^ (row & 7);
      bf16x8 b = *(const bf16x8*)&wl[swz];
      acc[t] = __builtin_amdgcn_mfma_f32_16x16x32_bf16(ahi, b, acc[t], 0, 0, 0);
      acc[t] = __builtin_amdgcn_mfma_f32_16x16x32_bf16(alo, b, acc[t], 0, 0, 0);
    }
  }

  int rowbase = tile * 128 + wave * 16 + kgrp * 4;
  #pragma unroll
  for (int t = 0; t < 4; ++t) {
    float as_v = a_s[t * 16 + l15], ad_v = a_d[t * 16 + l15];
    #pragma unroll
    for (int r = 0; r < 4; ++r) {
      int row = rowbase + r;
      float v = acc[t][r];
      bool ok = row < n;
      if (ok) xp1b[(size_t)row * HC + t * 16 + l15] = (__bf16)v;
      float ps = v * as_v, pd = v * ad_v;
      #pragma unroll
      for (int o = 1; o < 16; o <<= 1) {
        ps += __shfl_xor(ps, o, 16);
        pd += __shfl_xor(pd, o, 16);
      }
      if (ok && l15 == 0) {
        es1[row * 4 + t] = ps;
        ed1[row * 4 + t] = pd;
      }
    }
  }
}

// ---------------- fused A: [hist blocks | gemm tiles 0..ta) ----------------
__global__ __launch_bounds__(512) void fused_hg(
    const int* __restrict__ ei, int* __restrict__ blkhistT, int* __restrict__ btot,
    int E, int ET, int nbuck, int nblk,
    const float* __restrict__ x, const __bf16* __restrict__ Wt,
    const float* __restrict__ a_s, const float* __restrict__ a_d,
    __bf16* __restrict__ xp1b, float* __restrict__ es1, float* __restrict__ ed1, int n) {
  __shared__ __align__(16) char smem[32768];
  if ((int)blockIdx.x >= nblk) {
    gemm1_body(smem, (int)blockIdx.x - nblk, x, Wt, a_s, a_d, xp1b, es1, ed1, n);
    return;
  }
  int* hist = (int*)smem;
  int tid = threadIdx.x, blk = blockIdx.x;
  hist[tid] = 0;
  __syncthreads();
  int base = blk * CHUNK;
  #pragma unroll
  for (int it = 0; it < CHUNK / 2048; ++it) {   // 4 iters, 4 edges/thread
    int e = base + it * 2048 + tid * 4;
    if (e + 3 < E) {
      int4 d4 = *(const int4*)&ei[E + e];
      atomicAdd(&hist[d4.x >> NB_SH], 1);
      atomicAdd(&hist[d4.y >> NB_SH], 1);
      atomicAdd(&hist[d4.z >> NB_SH], 1);
      atomicAdd(&hist[d4.w >> NB_SH], 1);
    } else {
      #pragma unroll
      for (int k = 0; k < 4; ++k) {
        int ee = e + k;
        if (ee < ET) {
          int d = (ee < E) ? ei[E + ee] : (ee - E);
          atomicAdd(&hist[d >> NB_SH], 1);
        }
      }
    }
  }
  __syncthreads();
  for (int i = tid; i < nbuck; i += 512) {
    int c = hist[i];
    blkhistT[(size_t)i * nblk + blk] = c;
    if (c) atomicAdd(&btot[i], c);
  }
}

// ---------------- CSR 2: small exclusive scan -> bucket starts ----------------
__global__ __launch_bounds__(512) void bscan_kernel(
    const int* __restrict__ btot, int* __restrict__ bstart,
    int* __restrict__ offs, int nbuck, int ET, int n) {
  __shared__ int sm[512];
  int tid = threadIdx.x;
  int total = (tid < nbuck) ? btot[tid] : 0;
  sm[tid] = total; __syncthreads();
  for (int o = 1; o < 512; o <<= 1) {
    int v = (tid >= o) ? sm[tid - o] : 0;
    __syncthreads();
    sm[tid] += v;
    __syncthreads();
  }
  if (tid < nbuck) bstart[tid] = sm[tid] - total;   // exclusive
  if (tid == 0) { bstart[nbuck] = ET; offs[n] = ET; }
}

// ---------------- fused B: [curs blocks | gemm tiles ta..ta+tb) ----------------
__global__ __launch_bounds__(512) void fused_cg(
    const int* __restrict__ blkhistT, const int* __restrict__ bstart,
    int* __restrict__ cur, int nblk, int nbuck, int tile0,
    const float* __restrict__ x, const __bf16* __restrict__ Wt,
    const float* __restrict__ a_s, const float* __restrict__ a_d,
    __bf16* __restrict__ xp1b, float* __restrict__ es1, float* __restrict__ ed1, int n) {
  __shared__ __align__(16) char smem[32768];
  if ((int)blockIdx.x >= nbuck) {
    gemm1_body(smem, tile0 + (int)blockIdx.x - nbuck, x, Wt, a_s, a_d, xp1b, es1, ed1, n);
    return;
  }
  int* sm = (int*)smem;
  int b = blockIdx.x, tid = threadIdx.x;
  int run = bstart[b];
  for (int c = 0; c < nblk; c += 512) {
    int idx = c + tid;
    int v = (idx < nblk) ? blkhistT[(size_t)b * nblk + idx] : 0;
    sm[tid] = v; __syncthreads();
    for (int o = 1; o < 512; o <<= 1) {
      int x2 = (tid >= o) ? sm[tid - o] : 0;
      __syncthreads();
      sm[tid] += x2;
      __syncthreads();
    }
    if (idx < nblk) cur[(size_t)idx * nbuck + b] = run + sm[tid] - v;
    run += sm[511];
    __syncthreads();
  }
}

// ---------------- fused C: [scatter1 blocks | gemm tiles ..) ----------------
__global__ __launch_bounds__(512) void fused_sg(
    const int* __restrict__ ei, const int* __restrict__ cur,
    unsigned int* __restrict__ pairs, int E, int ET, int nbuck, int nsc, int tile0,
    const float* __restrict__ x, const __bf16* __restrict__ Wt,
    const float* __restrict__ a_s, const float* __restrict__ a_d,
    __bf16* __restrict__ xp1b, float* __restrict__ es1, float* __restrict__ ed1, int n) {
  __shared__ __align__(16) char smem[71680];
  if ((int)blockIdx.x >= nsc) {
    gemm1_body(smem, tile0 + (int)blockIdx.x - nsc, x, Wt, a_s, a_d, xp1b, es1, ed1, n);
    return;
  }
  int* hs   = (int*)smem;                         // 512
  int* addb = (int*)(smem + 2048);                // 512
  int* lcnt = (int*)(smem + 4096);                // 512
  unsigned int* lout = (unsigned int*)(smem + 6144);   // CHUNK
  int* ldst = (int*)(smem + 6144 + CHUNK * 4);         // CHUNK
  int tid = threadIdx.x, blk = blockIdx.x, base = blk * CHUNK;
  hs[tid] = 0; lcnt[tid] = 0;
  __syncthreads();
  int se[16], de[16];
  #pragma unroll
  for (int it = 0; it < CHUNK / 2048; ++it) {
    int e = base + it * 2048 + tid * 4;
    if (e + 3 < E) {
      int4 s4 = *(const int4*)&ei[e];
      int4 d4 = *(const int4*)&ei[E + e];
      se[it * 4 + 0] = s4.x; de[it * 4 + 0] = d4.x; atomicAdd(&hs[d4.x >> NB_SH], 1);
      se[it * 4 + 1] = s4.y; de[it * 4 + 1] = d4.y; atomicAdd(&hs[d4.y >> NB_SH], 1);
      se[it * 4 + 2] = s4.z; de[it * 4 + 2] = d4.z; atomicAdd(&hs[d4.z >> NB_SH], 1);
      se[it * 4 + 3] = s4.w; de[it * 4 + 3] = d4.w; atomicAdd(&hs[d4.w >> NB_SH], 1);
    } else {
      #pragma unroll
      for (int k = 0; k < 4; ++k) {
        int ee = e + k;
        int s = 0, d = 0;
        if (ee < ET) {
          if (ee < E) { s = ei[ee]; d = ei[E + ee]; }
          else        { s = ee - E; d = s; }
          atomicAdd(&hs[d >> NB_SH], 1);
        }
        se[it * 4 + k] = s; de[it * 4 + k] = d;
      }
    }
  }
  __syncthreads();
  int t = hs[tid];
  for (int o = 1; o < 512; o <<= 1) {
    int v = (tid >= o) ? hs[tid - o] : 0;
    __syncthreads();
    hs[tid] += v;
    __syncthreads();
  }
  int lofs = hs[tid] - t;
  __syncthreads();
  hs[tid] = lofs;
  addb[tid] = ((tid < nbuck) ? cur[(size_t)blk * nbuck + tid] : 0) - lofs;
  __syncthreads();
  #pragma unroll
  for (int it = 0; it < CHUNK / 2048; ++it) {
    #pragma unroll
    for (int k = 0; k < 4; ++k) {
      int e = base + it * 2048 + tid * 4 + k;
      if (e < ET) {
        int b = de[it * 4 + k] >> NB_SH;
        int pos = hs[b] + atomicAdd(&lcnt[b], 1);
        lout[pos] = (unsigned)se[it * 4 + k] |
                    ((unsigned)(de[it * 4 + k] & NB_MASK) << SRC_BITS);
        ldst[pos] = addb[b] + pos;
      }
    }
  }
  __syncthreads();
  int len = min(CHUNK, ET - base);
  for (int i = tid; i < len; i += 512) pairs[ldst[i]] = lout[i];
}

// ---------------- fused D: [place2 blocks | gemm tiles ..) ----------------
__global__ __launch_bounds__(512) void fused_pg(
    const unsigned int* __restrict__ pairs, const int* __restrict__ bstart,
    int* __restrict__ offs, int* __restrict__ srcs, int n, int nbuck, int tile0,
    const float* __restrict__ x, const __bf16* __restrict__ Wt,
    const float* __restrict__ a_s, const float* __restrict__ a_d,
    __bf16* __restrict__ xp1b, float* __restrict__ es1, float* __restrict__ ed1) {
  __shared__ __align__(16) char smem[53248];
  if ((int)blockIdx.x >= nbuck) {
    gemm1_body(smem, tile0 + (int)blockIdx.x - nbuck, x, Wt, a_s, a_d, xp1b, es1, ed1, n);
    return;
  }
  unsigned int* lin = (unsigned int*)smem;             // LEN_CAP
  unsigned int* lou = (unsigned int*)(smem + 24576);   // LEN_CAP
  int* lhs  = (int*)(smem + 49152);                    // 256
  int* lcnt = (int*)(smem + 50176);                    // 256
  int* sm   = (int*)(smem + 51200);                    // 512
  int b = blockIdx.x, tid = threadIdx.x;
  int rbeg = bstart[b], rend = bstart[b + 1], len = rend - rbeg;
  int node0 = b << NB_SH;
  int nloc = min(256, n - node0);
  if (tid < 256) { lhs[tid] = 0; lcnt[tid] = 0; }
  __syncthreads();
  if (len <= LEN_CAP) {
    for (int i = tid; i < len; i += 512) {
      unsigned p = pairs[rbeg + i];
      lin[i] = p;
      atomicAdd(&lhs[(p >> SRC_BITS) & NB_MASK], 1);
    }
    __syncthreads();
    int t = (tid < 256) ? lhs[tid] : 0;
    sm[tid] = t; __syncthreads();
    for (int o = 1; o < 512; o <<= 1) {
      int v = (tid >= o) ? sm[tid - o] : 0;
      __syncthreads();
      sm[tid] += v;
      __syncthreads();
    }
    int excl = sm[tid] - t;
    if (tid < nloc) offs[node0 + tid] = rbeg + excl;
    if (tid < 256) lhs[tid] = excl;
    __syncthreads();
    for (int i = tid; i < len; i += 512) {
      unsigned p = lin[i];
      int dl = (p >> SRC_BITS) & NB_MASK;
      int pos = lhs[dl] + atomicAdd(&lcnt[dl], 1);
      lou[pos] = p & SRC_MASK;
    }
    __syncthreads();
    for (int i = tid; i < len; i += 512) srcs[rbeg + i] = (int)lou[i];
  } else {
    for (int i = tid; i < len; i += 512)
      atomicAdd(&lhs[(pairs[rbeg + i] >> SRC_BITS) & NB_MASK], 1);
    __syncthreads();
    int t = (tid < 256) ? lhs[tid] : 0;
    sm[tid] = t; __syncthreads();
    for (int o = 1; o < 512; o <<= 1) {
      int v = (tid >= o) ? sm[tid - o] : 0;
      __syncthreads();
      sm[tid] += v;
      __syncthreads();
    }
    int excl = sm[tid] - t;
    if (tid < nloc) offs[node0 + tid] = rbeg + excl;
    if (tid < 256) lhs[tid] = excl;
    __syncthreads();
    for (int i = tid; i < len; i += 512) {
      unsigned p = pairs[rbeg + i];
      int dl = (p >> SRC_BITS) & NB_MASK;
      int pos = lhs[dl] + atomicAdd(&lcnt[dl], 1);
      srcs[rbeg + pos] = (int)(p & SRC_MASK);
    }
  }
}

// ---------------- W1 prep (+ btot zero); runs FIRST in the stream ----------------
__global__ void wprep_kernel(const float* __restrict__ W1, __bf16* __restrict__ Wt,
                             int* __restrict__ btot, int nbuck) {
  int i = blockIdx.x * blockDim.x + threadIdx.x;   // over 256*64
  if (i < nbuck) btot[i] = 0;
  if (i >= IN_DIM * HC) return;
  int k = i >> 6, nn = i & 63;
  Wt[nn * IN_DIM + k] = (__bf16)W1[i];
}

// ---------------- layer 1 aggregation: pair-vectorized two-phase softmax, bf16 h out ----------------
__global__ __launch_bounds__(256) void agg1_csr(
    const int* __restrict__ offs, const int* __restrict__ srcs,
    const float* __restrict__ es1, const float* __restrict__ ed1,
    const __bf16* __restrict__ xp1b, const float* __restrict__ b1,
    __bf16* __restrict__ hb, int n) {
  __shared__ float lds[4][16 * 4 * 2];
  int wave = threadIdx.x >> 6;
  int wid = (blockIdx.x * 256 + threadIdx.x) >> 6;
  if (wid >= n) return;
  int lane = threadIdx.x & 63;
  int eidx = lane >> 2, hA = lane & 3;     // phase-A view
  int a = lane & 31, half = lane >> 5;     // phase-B view
  int ch0 = a * 2, headB = a >> 3;
  int beg = offs[wid], end = offs[wid + 1];
  float edh = ed1[wid * 4 + hA];
  float zacc = 0.f, acc0 = 0.f, acc1 = 0.f;
  const char* xbase = (const char*)xp1b + ch0 * 2;
  float* myl = lds[wave];

  for (int e0 = beg; e0 < end; e0 += 16) {
    int cnt = min(16, end - e0);
    float ex = 0.f;
    int s = 0;
    if (eidx < cnt) {
      s = srcs[e0 + eidx];
      ex = __expf(lrelu(es1[s * 4 + hA] + edh));
    }
    zacc += ex;
    myl[lane * 2]     = ex;
    myl[lane * 2 + 1] = __int_as_float(s * (int)(HC * sizeof(__bf16)));
    if (cnt == 16) {
      float2 ao[8];
      #pragma unroll
      for (int jp = 0; jp < 8; ++jp)
        ao[jp] = *(const float2*)&myl[((jp * 2 + half) * 4 + headB) * 2];
      unsigned wj[8];
      #pragma unroll
      for (int jp = 0; jp < 8; ++jp)
        wj[jp] = *(const unsigned*)(xbase + __float_as_int(ao[jp].y));
      #pragma unroll
      for (int jp = 0; jp < 8; ++jp) {
        float f0 = __int_as_float((int)(wj[jp] << 16));
        float f1 = __int_as_float((int)(wj[jp] & 0xffff0000u));
        acc0 = fmaf(ao[jp].x, f0, acc0);
        acc1 = fmaf(ao[jp].x, f1, acc1);
      }
    } else {
      int jpmax = (cnt + 1 - half) >> 1;
      #pragma unroll 4
      for (int jp = 0; jp < jpmax; ++jp) {
        float2 ao = *(const float2*)&myl[((jp * 2 + half) * 4 + headB) * 2];
        unsigned w = *(const unsigned*)(xbase + __float_as_int(ao.y));
        float f0 = __int_as_float((int)(w << 16));
        float f1 = __int_as_float((int)(w & 0xffff0000u));
        acc0 = fmaf(ao.x, f0, acc0);
        acc1 = fmaf(ao.x, f1, acc1);
      }
    }
  }

  float z = zacc;
  z += __shfl_xor(z, 4); z += __shfl_xor(z, 8);
  z += __shfl_xor(z, 16); z += __shfl_xor(z, 32);
  float zc = __shfl(z, headB);
  acc0 += __shfl_xor(acc0, 32);
  acc1 += __shfl_xor(acc1, 32);
  if (half == 0) {
    float inv = 1.f / (zc + 1e-16f);
    __bf16 r0 = (__bf16)fmaxf(fmaf(acc0, inv, b1[ch0]), 0.f);
    __bf16 r1 = (__bf16)fmaxf(fmaf(acc1, inv, b1[ch0 + 1]), 0.f);
    unsigned pk = ((unsigned)*(unsigned short*)&r0) |
                  (((unsigned)*(unsigned short*)&r1) << 16);
    *(unsigned*)&hb[(size_t)wid * HC + ch0] = pk;
  }
}

// ---------------- layer 2 projection via MFMA: xp2 = hb @ W2 (bf16 A, split-bf16 W2) ----------------
__global__ __launch_bounds__(256) void layer2_mfma(
    const __bf16* __restrict__ hb, const float* __restrict__ W2,
    const float* __restrict__ a_s2, const float* __restrict__ a_d2,
    __bf16* __restrict__ xp2b, float* __restrict__ es2, float* __restrict__ ed2, int n) {
  int tid = threadIdx.x;
  int wave = tid >> 6, lane = tid & 63;
  int l15 = lane & 15, kgrp = lane >> 4;
  int rowA = blockIdx.x * 64 + wave * 16 + l15;
  const __bf16* hrow = hb + (size_t)(rowA < n ? rowA : (n - 1)) * HC;

  bf16x8 av[2];
  av[0] = *(const bf16x8*)(hrow + kgrp * 8);
  av[1] = *(const bf16x8*)(hrow + 32 + kgrp * 8);

  f32x4 acc[3] = {};
  #pragma unroll
  for (int c = 0; c < 2; ++c) {
    #pragma unroll
    for (int t = 0; t < 3; ++t) {
      int col = t * 16 + l15;
      bool okc = col < OUT_DIM;
      bf16x8 bhi, blo;
      #pragma unroll
      for (int i = 0; i < 8; ++i) {
        int k = c * 32 + kgrp * 8 + i;
        float w = okc ? W2[k * OUT_DIM + col] : 0.f;
        __bf16 wh = (__bf16)w;
        bhi[i] = wh;
        blo[i] = (__bf16)(w - (float)wh);
      }
      acc[t] = __builtin_amdgcn_mfma_f32_16x16x32_bf16(av[c], bhi, acc[t], 0, 0, 0);
      acc[t] = __builtin_amdgcn_mfma_f32_16x16x32_bf16(av[c], blo, acc[t], 0, 0, 0);
    }
  }

  int rowbase = blockIdx.x * 64 + wave * 16 + kgrp * 4;
  #pragma unroll
  for (int r = 0; r < 4; ++r) {
    int row = rowbase + r;
    bool ok = row < n;
    float ps = 0.f, pd = 0.f;
    #pragma unroll
    for (int t = 0; t < 3; ++t) {
      int col = t * 16 + l15;
      if (col < OUT_DIM) {
        float v = acc[t][r];
        if (ok) xp2b[(size_t)row * OUT_DIM + col] = (__bf16)v;
        ps = fmaf(v, a_s2[col], ps);
        pd = fmaf(v, a_d2[col], pd);
      }
    }
    #pragma unroll
    for (int o = 1; o < 16; o <<= 1) {
      ps += __shfl_xor(ps, o, 16);
      pd += __shfl_xor(pd, o, 16);
    }
    if (ok && l15 == 0) { es2[row] = ps; ed2[row] = pd; }
  }
}

// ---------------- layer 2 aggregation: pair-vectorized two-phase softmax ----------------
__global__ __launch_bounds__(256) void agg2_csr(
    const int* __restrict__ offs, const int* __restrict__ srcs,
    const float* __restrict__ es2, const float* __restrict__ ed2,
    const __bf16* __restrict__ xp2b, const float* __restrict__ b2,
    float* __restrict__ out, int n) {
  __shared__ float lds[4][64 * 2];
  int wave = threadIdx.x >> 6;
  int wid = (blockIdx.x * 256 + threadIdx.x) >> 6;
  if (wid >= n) return;
  int lane = threadIdx.x & 63;
  int a = lane & 31, half = lane >> 5;
  int ch0 = a * 2;                        // valid when a < 20
  int beg = offs[wid], end = offs[wid + 1];
  float edv = ed2[wid];
  float zacc = 0.f, acc0 = 0.f, acc1 = 0.f;
  const char* xbase = (const char*)xp2b + ch0 * 2;
  float* myl = lds[wave];

  for (int e0 = beg; e0 < end; e0 += 64) {
    int cnt = min(64, end - e0);
    float ex = 0.f;
    int s = 0;
    if (lane < cnt) {
      s = srcs[e0 + lane];
      ex = __expf(lrelu(es2[s] + edv));
    }
    zacc += ex;
    myl[lane * 2]     = ex;
    myl[lane * 2 + 1] = __int_as_float(s * (int)(OUT_DIM * sizeof(__bf16)));
    if (a < 20) {
      int jpmax = (cnt + 1 - half) >> 1;
      int jp = 0;
      for (; jp + 8 <= jpmax; jp += 8) {
        float2 ao[8];
        #pragma unroll
        for (int k = 0; k < 8; ++k)
          ao[k] = *(const float2*)&myl[((jp + k) * 2 + half) * 2];
        unsigned wj[8];
        #pragma unroll
        for (int k = 0; k < 8; ++k)
          wj[k] = *(const unsigned*)(xbase + __float_as_int(ao[k].y));
        #pragma unroll
        for (int k = 0; k < 8; ++k) {
          float f0 = __int_as_float((int)(wj[k] << 16));
          float f1 = __int_as_float((int)(wj[k] & 0xffff0000u));
          acc0 = fmaf(ao[k].x, f0, acc0);
          acc1 = fmaf(ao[k].x, f1, acc1);
        }
      }
      #pragma unroll 4
      for (; jp < jpmax; ++jp) {
        float2 ao = *(const float2*)&myl[(jp * 2 + half) * 2];
        unsigned w = *(const unsigned*)(xbase + __float_as_int(ao.y));
        float f0 = __int_as_float((int)(w << 16));
        float f1 = __int_as_float((int)(w & 0xffff0000u));
        acc0 = fmaf(ao.x, f0, acc0);
        acc1 = fmaf(ao.x, f1, acc1);
      }
    }
  }

  float z = zacc;
  #pragma unroll
  for (int o = 1; o < 64; o <<= 1) z += __shfl_xor(z, o);
  acc0 += __shfl_xor(acc0, 32);
  acc1 += __shfl_xor(acc1, 32);
  if (half == 0 && a < 20) {
    float inv = 1.f / (z + 1e-16f);
    float2 r;
    r.x = fmaf(acc0, inv, b2[ch0]);
    r.y = fmaf(acc1, inv, b2[ch0 + 1]);
    *(float2*)&out[(size_t)wid * OUT_DIM + ch0] = r;
  }
}

extern "C" void kernel_launch(void* const* d_in, const int* in_sizes, int n_in,
                              void* d_out, int out_size, void* d_ws, size_t ws_size,
                              hipStream_t stream) {
  const float* x    = (const float*)d_in[0];
  const int*   ei   = (const int*)d_in[1];
  const float* W1   = (const float*)d_in[2];
  const float* a_s1 = (const float*)d_in[3];
  const float* a_d1 = (const float*)d_in[4];
  const float* b1   = (const float*)d_in[5];
  const float* W2   = (const float*)d_in[6];
  const float* a_s2 = (const float*)d_in[7];
  const float* a_d2 = (const float*)d_in[8];
  const float* b2   = (const float*)d_in[9];

  int n  = in_sizes[0] / IN_DIM;
  int E  = in_sizes[1] / 2;
  int ET = E + n;
  int nbuck = (n + 255) >> NB_SH;
  int nblk1 = (ET + CHUNK - 1) / CHUNK;
  int ntile = (n + 127) / 128;
  int ta = (ntile * 29) / 100;
  int tb = (ntile * 29) / 100;
  int tc = (ntile * 21) / 100;
  int td = ntile - ta - tb - tc;
  float* out = (float*)d_out;

  char* ws = (char*)d_ws;
  size_t off = 0;
  auto alloc = [&](size_t bytes) -> void* {
    void* p = ws + off;
    off = (off + bytes + 255) & ~(size_t)255;
    return p;
  };
  __bf16* xp1b     = (__bf16*)alloc((size_t)n * HC * 2);
  __bf16* xp2b     = (__bf16*)alloc((size_t)n * OUT_DIM * 2);
  __bf16* hb       = (__bf16*)alloc((size_t)n * HC * 2);
  float*  es1      = (float*)alloc((size_t)n * 4 * 4);
  float*  ed1      = (float*)alloc((size_t)n * 4 * 4);
  float*  es2      = (float*)alloc((size_t)n * 4);
  float*  ed2      = (float*)alloc((size_t)n * 4);
  int*    blkhistT = (int*)alloc((size_t)nblk1 * nbuck * 4);
  int*    cur      = (int*)alloc((size_t)nblk1 * nbuck * 4);
  int*    btot     = (int*)alloc((size_t)(nbuck + 1) * 4);
  int*    bstart   = (int*)alloc((size_t)(nbuck + 1) * 4);
  int*    offs     = (int*)alloc((size_t)(n + 1) * 4);
  int*    srcs     = (int*)alloc((size_t)ET * 4);
  unsigned int* pairs = (unsigned int*)alloc((size_t)ET * 4);
  __bf16* Wt       = (__bf16*)alloc((size_t)IN_DIM * HC * 2);

  wprep_kernel<<<(IN_DIM * HC + 255) / 256, 256, 0, stream>>>(W1, Wt, btot, nbuck);
  fused_hg<<<nblk1 + ta, 512, 0, stream>>>(ei, blkhistT, btot, E, ET, nbuck, nblk1,
                                           x, Wt, a_s1, a_d1, xp1b, es1, ed1, n);
  bscan_kernel<<<1, 512, 0, stream>>>(btot, bstart, offs, nbuck, ET, n);
  fused_cg<<<nbuck + tb, 512, 0, stream>>>(blkhistT, bstart, cur, nblk1, nbuck, ta,
                                           x, Wt, a_s1, a_d1, xp1b, es1, ed1, n);
  fused_sg<<<nblk1 + tc, 512, 0, stream>>>(ei, cur, pairs, E, ET, nbuck, nblk1, ta + tb,
                                           x, Wt, a_s1, a_d1, xp1b, es1, ed1, n);
  fused_pg<<<nbuck + td, 512, 0, stream>>>(pairs, bstart, offs, srcs, n, nbuck, ta + tb + tc,
                                           x, Wt, a_s1, a_d1, xp1b, es1, ed1);
  agg1_csr<<<(n * 64 + 255) / 256, 256, 0, stream>>>(offs, srcs, es1, ed1, xp1b, b1, hb, n);
  layer2_mfma<<<(n + 63) / 64, 256, 0, stream>>>(hb, W2, a_s2, a_d2, xp2b, es2, ed2, n);
  agg2_csr<<<(n * 64 + 255) / 256, 256, 0, stream>>>(offs, srcs, es2, ed2, xp2b, b2, out, n);
}

// Round 25
// 185.551 us; speedup vs baseline: 1.0501x; 1.0501x over previous
//
#include <hip/hip_runtime.h>
#include <hip/hip_bf16.h>

#define IN_DIM 256
#define HC     64    // H*C for layer 1
#define OUT_DIM 40
#define NEG    0.2f

#define NB_SH   8     // 256 nodes per bucket
#define NB_MASK 255
#define SRC_BITS 17   // n=100000 < 2^17
#define SRC_MASK 0x1FFFF
#define CHUNK   8192  // edges per scatter block
#define LEN_CAP 6144  // place2 LDS capacity (mean bucket len ~4450)

typedef __bf16 bf16x8 __attribute__((ext_vector_type(8)));
typedef float  f32x4  __attribute__((ext_vector_type(4)));

__device__ inline float lrelu(float v) { return fmaxf(v, NEG * v); }  // NEG<1

// ---------------- CSR 1: per-block bucket histogram (int4 loads, transposed out) ----------------
__global__ __launch_bounds__(256) void hist_kernel(
    const int* __restrict__ ei, int* __restrict__ blkhistT, int* __restrict__ btot,
    int E, int ET, int nbuck, int nblk) {
  __shared__ int hist[512];
  int tid = threadIdx.x;
  hist[tid] = 0; hist[tid + 256] = 0;
  __syncthreads();
  int base = blockIdx.x * CHUNK;
  #pragma unroll
  for (int it = 0; it < CHUNK / 1024; ++it) {   // 8 iters, 4 edges/thread
    int e = base + it * 1024 + tid * 4;
    if (e + 3 < E) {
      int4 d4 = *(const int4*)&ei[E + e];
      atomicAdd(&hist[d4.x >> NB_SH], 1);
      atomicAdd(&hist[d4.y >> NB_SH], 1);
      atomicAdd(&hist[d4.z >> NB_SH], 1);
      atomicAdd(&hist[d4.w >> NB_SH], 1);
    } else {
      #pragma unroll
      for (int k = 0; k < 4; ++k) {
        int ee = e + k;
        if (ee < ET) {
          int d = (ee < E) ? ei[E + ee] : (ee - E);
          atomicAdd(&hist[d >> NB_SH], 1);
        }
      }
    }
  }
  __syncthreads();
  for (int i = tid; i < nbuck; i += 256) {
    int c = hist[i];
    blkhistT[(size_t)i * nblk + blockIdx.x] = c;
    if (c) atomicAdd(&btot[i], c);
  }
}

// ---------------- CSR 2: small exclusive scan -> bucket starts ----------------
__global__ __launch_bounds__(512) void bscan_kernel(
    const int* __restrict__ btot, int* __restrict__ bstart,
    int* __restrict__ offs, int nbuck, int ET, int n) {
  __shared__ int sm[512];
  int tid = threadIdx.x;
  int total = (tid < nbuck) ? btot[tid] : 0;
  sm[tid] = total; __syncthreads();
  for (int o = 1; o < 512; o <<= 1) {
    int v = (tid >= o) ? sm[tid - o] : 0;
    __syncthreads();
    sm[tid] += v;
    __syncthreads();
  }
  if (tid < nbuck) bstart[tid] = sm[tid] - total;   // exclusive
  if (tid == 0) { bstart[nbuck] = ET; offs[n] = ET; }
}

// ---------------- CSR 3: per-(block,bucket) cursors; coalesced transposed reads ----------------
__global__ __launch_bounds__(256) void curs_kernel(
    const int* __restrict__ blkhistT, const int* __restrict__ bstart,
    int* __restrict__ cur, int nblk, int nbuck) {
  __shared__ int sm[256];
  int b = blockIdx.x, tid = threadIdx.x;
  int run = bstart[b];
  for (int c = 0; c < nblk; c += 256) {
    int idx = c + tid;
    int v = (idx < nblk) ? blkhistT[(size_t)b * nblk + idx] : 0;
    sm[tid] = v; __syncthreads();
    for (int o = 1; o < 256; o <<= 1) {
      int x = (tid >= o) ? sm[tid - o] : 0;
      __syncthreads();
      sm[tid] += x;
      __syncthreads();
    }
    if (idx < nblk) cur[(size_t)idx * nbuck + b] = run + sm[tid] - v;
    run += sm[255];
    __syncthreads();
  }
}

// ---------------- gemm1 body (512 threads, 128 rows/block, 32KB W in smem) ----------------
__device__ __forceinline__ void gemm1_body(
    char* smem, int tile,
    const float* __restrict__ x, const __bf16* __restrict__ Wt,
    const float* __restrict__ a_s, const float* __restrict__ a_d,
    __bf16* __restrict__ xp1b, float* __restrict__ es1, float* __restrict__ ed1, int n) {
  uint4* wl = (uint4*)smem;   // 32 KB, swizzled 16B units
  int tid = threadIdx.x;
  const uint4* gw = (const uint4*)Wt;
  #pragma unroll
  for (int it = 0; it < 4; ++it) {
    int c16 = it * 512 + tid;
    int row = c16 >> 5;
    int swz = c16 ^ (row & 7);
    wl[swz] = gw[c16];
  }
  __syncthreads();

  int wave = tid >> 6, lane = tid & 63;
  int l15 = lane & 15, kgrp = lane >> 4;
  int rowA = tile * 128 + wave * 16 + l15;
  bool okA = rowA < n;
  const float* xrow = x + (size_t)(okA ? rowA : (n - 1)) * IN_DIM;

  f32x4 va[8][2];
  #pragma unroll
  for (int c = 0; c < 8; ++c) {
    int k0 = c * 32 + kgrp * 8;
    va[c][0] = *(const f32x4*)(xrow + k0);
    va[c][1] = *(const f32x4*)(xrow + k0 + 4);
  }
  __builtin_amdgcn_sched_barrier(0);

  f32x4 acc[4] = {};
  #pragma unroll
  for (int c = 0; c < 8; ++c) {
    bf16x8 ahi, alo;
    #pragma unroll
    for (int i = 0; i < 4; ++i) {
      float f0 = va[c][0][i], f1 = va[c][1][i];
      __bf16 h0 = (__bf16)f0, h1 = (__bf16)f1;
      ahi[i]     = h0;
      ahi[4 + i] = h1;
      alo[i]     = (__bf16)(f0 - (float)h0);
      alo[4 + i] = (__bf16)(f1 - (float)h1);
    }
    #pragma unroll
    for (int t = 0; t < 4; ++t) {
      int row  = t * 16 + l15;
      int unit = row * 32 + c * 4 + kgrp;
      int swz  = unit ^ (row & 7);
      bf16x8 b = *(const bf16x8*)&wl[swz];
      acc[t] = __builtin_amdgcn_mfma_f32_16x16x32_bf16(ahi, b, acc[t], 0, 0, 0);
      acc[t] = __builtin_amdgcn_mfma_f32_16x16x32_bf16(alo, b, acc[t], 0, 0, 0);
    }
  }

  int rowbase = tile * 128 + wave * 16 + kgrp * 4;
  #pragma unroll
  for (int t = 0; t < 4; ++t) {
    float as_v = a_s[t * 16 + l15], ad_v = a_d[t * 16 + l15];
    #pragma unroll
    for (int r = 0; r < 4; ++r) {
      int row = rowbase + r;
      float v = acc[t][r];
      bool ok = row < n;
      if (ok) xp1b[(size_t)row * HC + t * 16 + l15] = (__bf16)v;
      float ps = v * as_v, pd = v * ad_v;
      #pragma unroll
      for (int o = 1; o < 16; o <<= 1) {
        ps += __shfl_xor(ps, o, 16);
        pd += __shfl_xor(pd, o, 16);
      }
      if (ok && l15 == 0) {
        es1[row * 4 + t] = ps;
        ed1[row * 4 + t] = pd;
      }
    }
  }
}

// ---------------- fused 1: [scatter1 blocks | gemm1 tiles 0..t0) ----------------
__global__ __launch_bounds__(512) void fused_sg(
    const int* __restrict__ ei, const int* __restrict__ cur,
    unsigned int* __restrict__ pairs, int E, int ET, int nbuck, int nsc,
    const float* __restrict__ x, const __bf16* __restrict__ Wt,
    const float* __restrict__ a_s, const float* __restrict__ a_d,
    __bf16* __restrict__ xp1b, float* __restrict__ es1, float* __restrict__ ed1, int n) {
  __shared__ __align__(16) char smem[71680];
  if ((int)blockIdx.x >= nsc) {
    gemm1_body(smem, (int)blockIdx.x - nsc, x, Wt, a_s, a_d, xp1b, es1, ed1, n);
    return;
  }
  // ---- scatter1 path ----
  int* hs   = (int*)smem;                         // 512
  int* addb = (int*)(smem + 2048);                // 512
  int* lcnt = (int*)(smem + 4096);                // 512
  unsigned int* lout = (unsigned int*)(smem + 6144);   // CHUNK
  int* ldst = (int*)(smem + 6144 + CHUNK * 4);         // CHUNK
  int tid = threadIdx.x, blk = blockIdx.x, base = blk * CHUNK;
  hs[tid] = 0; lcnt[tid] = 0;
  __syncthreads();
  int se[16], de[16];
  #pragma unroll
  for (int it = 0; it < CHUNK / 2048; ++it) {
    int e = base + it * 2048 + tid * 4;
    if (e + 3 < E) {
      int4 s4 = *(const int4*)&ei[e];
      int4 d4 = *(const int4*)&ei[E + e];
      se[it * 4 + 0] = s4.x; de[it * 4 + 0] = d4.x; atomicAdd(&hs[d4.x >> NB_SH], 1);
      se[it * 4 + 1] = s4.y; de[it * 4 + 1] = d4.y; atomicAdd(&hs[d4.y >> NB_SH], 1);
      se[it * 4 + 2] = s4.z; de[it * 4 + 2] = d4.z; atomicAdd(&hs[d4.z >> NB_SH], 1);
      se[it * 4 + 3] = s4.w; de[it * 4 + 3] = d4.w; atomicAdd(&hs[d4.w >> NB_SH], 1);
    } else {
      #pragma unroll
      for (int k = 0; k < 4; ++k) {
        int ee = e + k;
        int s = 0, d = 0;
        if (ee < ET) {
          if (ee < E) { s = ei[ee]; d = ei[E + ee]; }
          else        { s = ee - E; d = s; }
          atomicAdd(&hs[d >> NB_SH], 1);
        }
        se[it * 4 + k] = s; de[it * 4 + k] = d;
      }
    }
  }
  __syncthreads();
  int t = hs[tid];
  for (int o = 1; o < 512; o <<= 1) {
    int v = (tid >= o) ? hs[tid - o] : 0;
    __syncthreads();
    hs[tid] += v;
    __syncthreads();
  }
  int lofs = hs[tid] - t;
  __syncthreads();
  hs[tid] = lofs;
  addb[tid] = ((tid < nbuck) ? cur[(size_t)blk * nbuck + tid] : 0) - lofs;
  __syncthreads();
  #pragma unroll
  for (int it = 0; it < CHUNK / 2048; ++it) {
    #pragma unroll
    for (int k = 0; k < 4; ++k) {
      int e = base + it * 2048 + tid * 4 + k;
      if (e < ET) {
        int b = de[it * 4 + k] >> NB_SH;
        int pos = hs[b] + atomicAdd(&lcnt[b], 1);
        lout[pos] = (unsigned)se[it * 4 + k] |
                    ((unsigned)(de[it * 4 + k] & NB_MASK) << SRC_BITS);
        ldst[pos] = addb[b] + pos;
      }
    }
  }
  __syncthreads();
  int len = min(CHUNK, ET - base);
  for (int i = tid; i < len; i += 512) pairs[ldst[i]] = lout[i];
}

// ---------------- fused 2: [place2 blocks | gemm1 tiles t0..ntile) ----------------
__global__ __launch_bounds__(512) void fused_pg(
    const unsigned int* __restrict__ pairs, const int* __restrict__ bstart,
    int* __restrict__ offs, int* __restrict__ srcs, int n, int nbuck, int tile0,
    const float* __restrict__ x, const __bf16* __restrict__ Wt,
    const float* __restrict__ a_s, const float* __restrict__ a_d,
    __bf16* __restrict__ xp1b, float* __restrict__ es1, float* __restrict__ ed1) {
  __shared__ __align__(16) char smem[53248];
  if ((int)blockIdx.x >= nbuck) {
    gemm1_body(smem, tile0 + (int)blockIdx.x - nbuck, x, Wt, a_s, a_d, xp1b, es1, ed1, n);
    return;
  }
  // ---- place2 path ----
  unsigned int* lin = (unsigned int*)smem;             // LEN_CAP
  unsigned int* lou = (unsigned int*)(smem + 24576);   // LEN_CAP
  int* lhs  = (int*)(smem + 49152);                    // 256
  int* lcnt = (int*)(smem + 50176);                    // 256
  int* sm   = (int*)(smem + 51200);                    // 512
  int b = blockIdx.x, tid = threadIdx.x;
  int rbeg = bstart[b], rend = bstart[b + 1], len = rend - rbeg;
  int node0 = b << NB_SH;
  int nloc = min(256, n - node0);
  if (tid < 256) { lhs[tid] = 0; lcnt[tid] = 0; }
  __syncthreads();
  if (len <= LEN_CAP) {
    for (int i = tid; i < len; i += 512) {
      unsigned p = pairs[rbeg + i];
      lin[i] = p;
      atomicAdd(&lhs[(p >> SRC_BITS) & NB_MASK], 1);
    }
    __syncthreads();
    int t = (tid < 256) ? lhs[tid] : 0;
    sm[tid] = t; __syncthreads();
    for (int o = 1; o < 512; o <<= 1) {
      int v = (tid >= o) ? sm[tid - o] : 0;
      __syncthreads();
      sm[tid] += v;
      __syncthreads();
    }
    int excl = sm[tid] - t;
    if (tid < nloc) offs[node0 + tid] = rbeg + excl;
    if (tid < 256) lhs[tid] = excl;
    __syncthreads();
    for (int i = tid; i < len; i += 512) {
      unsigned p = lin[i];
      int dl = (p >> SRC_BITS) & NB_MASK;
      int pos = lhs[dl] + atomicAdd(&lcnt[dl], 1);
      lou[pos] = p & SRC_MASK;
    }
    __syncthreads();
    for (int i = tid; i < len; i += 512) srcs[rbeg + i] = (int)lou[i];
  } else {
    for (int i = tid; i < len; i += 512)
      atomicAdd(&lhs[(pairs[rbeg + i] >> SRC_BITS) & NB_MASK], 1);
    __syncthreads();
    int t = (tid < 256) ? lhs[tid] : 0;
    sm[tid] = t; __syncthreads();
    for (int o = 1; o < 512; o <<= 1) {
      int v = (tid >= o) ? sm[tid - o] : 0;
      __syncthreads();
      sm[tid] += v;
      __syncthreads();
    }
    int excl = sm[tid] - t;
    if (tid < nloc) offs[node0 + tid] = rbeg + excl;
    if (tid < 256) lhs[tid] = excl;
    __syncthreads();
    for (int i = tid; i < len; i += 512) {
      unsigned p = pairs[rbeg + i];
      int dl = (p >> SRC_BITS) & NB_MASK;
      int pos = lhs[dl] + atomicAdd(&lcnt[dl], 1);
      srcs[rbeg + pos] = (int)(p & SRC_MASK);
    }
  }
}

// ---------------- W1 prep (+ btot zero); runs FIRST in the stream ----------------
__global__ void wprep_kernel(const float* __restrict__ W1, __bf16* __restrict__ Wt,
                             int* __restrict__ btot, int nbuck) {
  int i = blockIdx.x * blockDim.x + threadIdx.x;   // over 256*64
  if (i < nbuck) btot[i] = 0;
  if (i >= IN_DIM * HC) return;
  int k = i >> 6, nn = i & 63;
  Wt[nn * IN_DIM + k] = (__bf16)W1[i];
}

// ---------------- layer 1 aggregation: pair-vectorized two-phase softmax, bf16 h out ----------------
__global__ __launch_bounds__(256) void agg1_csr(
    const int* __restrict__ offs, const int* __restrict__ srcs,
    const float* __restrict__ es1, const float* __restrict__ ed1,
    const __bf16* __restrict__ xp1b, const float* __restrict__ b1,
    __bf16* __restrict__ hb, int n) {
  __shared__ float lds[4][16 * 4 * 2];
  int wave = threadIdx.x >> 6;
  int wid = (blockIdx.x * 256 + threadIdx.x) >> 6;
  if (wid >= n) return;
  int lane = threadIdx.x & 63;
  int eidx = lane >> 2, hA = lane & 3;     // phase-A view
  int a = lane & 31, half = lane >> 5;     // phase-B view
  int ch0 = a * 2, headB = a >> 3;
  int beg = offs[wid], end = offs[wid + 1];
  float edh = ed1[wid * 4 + hA];
  float zacc = 0.f, acc0 = 0.f, acc1 = 0.f;
  const char* xbase = (const char*)xp1b + ch0 * 2;
  float* myl = lds[wave];

  for (int e0 = beg; e0 < end; e0 += 16) {
    int cnt = min(16, end - e0);
    float ex = 0.f;
    int s = 0;
    if (eidx < cnt) {
      s = srcs[e0 + eidx];
      ex = __expf(lrelu(es1[s * 4 + hA] + edh));
    }
    zacc += ex;
    myl[lane * 2]     = ex;
    myl[lane * 2 + 1] = __int_as_float(s * (int)(HC * sizeof(__bf16)));
    if (cnt == 16) {
      float2 ao[8];
      #pragma unroll
      for (int jp = 0; jp < 8; ++jp)
        ao[jp] = *(const float2*)&myl[((jp * 2 + half) * 4 + headB) * 2];
      unsigned wj[8];
      #pragma unroll
      for (int jp = 0; jp < 8; ++jp)
        wj[jp] = *(const unsigned*)(xbase + __float_as_int(ao[jp].y));
      #pragma unroll
      for (int jp = 0; jp < 8; ++jp) {
        float f0 = __int_as_float((int)(wj[jp] << 16));
        float f1 = __int_as_float((int)(wj[jp] & 0xffff0000u));
        acc0 = fmaf(ao[jp].x, f0, acc0);
        acc1 = fmaf(ao[jp].x, f1, acc1);
      }
    } else {
      int jpmax = (cnt + 1 - half) >> 1;
      #pragma unroll 4
      for (int jp = 0; jp < jpmax; ++jp) {
        float2 ao = *(const float2*)&myl[((jp * 2 + half) * 4 + headB) * 2];
        unsigned w = *(const unsigned*)(xbase + __float_as_int(ao.y));
        float f0 = __int_as_float((int)(w << 16));
        float f1 = __int_as_float((int)(w & 0xffff0000u));
        acc0 = fmaf(ao.x, f0, acc0);
        acc1 = fmaf(ao.x, f1, acc1);
      }
    }
  }

  float z = zacc;
  z += __shfl_xor(z, 4); z += __shfl_xor(z, 8);
  z += __shfl_xor(z, 16); z += __shfl_xor(z, 32);
  float zc = __shfl(z, headB);
  acc0 += __shfl_xor(acc0, 32);
  acc1 += __shfl_xor(acc1, 32);
  if (half == 0) {
    float inv = 1.f / (zc + 1e-16f);
    __bf16 r0 = (__bf16)fmaxf(fmaf(acc0, inv, b1[ch0]), 0.f);
    __bf16 r1 = (__bf16)fmaxf(fmaf(acc1, inv, b1[ch0 + 1]), 0.f);
    unsigned pk = ((unsigned)*(unsigned short*)&r0) |
                  (((unsigned)*(unsigned short*)&r1) << 16);
    *(unsigned*)&hb[(size_t)wid * HC + ch0] = pk;
  }
}

// ---------------- layer 2 projection via MFMA: xp2 = hb @ W2 (bf16 A, split-bf16 W2) ----------------
__global__ __launch_bounds__(256) void layer2_mfma(
    const __bf16* __restrict__ hb, const float* __restrict__ W2,
    const float* __restrict__ a_s2, const float* __restrict__ a_d2,
    __bf16* __restrict__ xp2b, float* __restrict__ es2, float* __restrict__ ed2, int n) {
  int tid = threadIdx.x;
  int wave = tid >> 6, lane = tid & 63;
  int l15 = lane & 15, kgrp = lane >> 4;
  int rowA = blockIdx.x * 64 + wave * 16 + l15;
  const __bf16* hrow = hb + (size_t)(rowA < n ? rowA : (n - 1)) * HC;

  bf16x8 av[2];
  av[0] = *(const bf16x8*)(hrow + kgrp * 8);
  av[1] = *(const bf16x8*)(hrow + 32 + kgrp * 8);

  f32x4 acc[3] = {};
  #pragma unroll
  for (int c = 0; c < 2; ++c) {
    #pragma unroll
    for (int t = 0; t < 3; ++t) {
      int col = t * 16 + l15;
      bool okc = col < OUT_DIM;
      bf16x8 bhi, blo;
      #pragma unroll
      for (int i = 0; i < 8; ++i) {
        int k = c * 32 + kgrp * 8 + i;
        float w = okc ? W2[k * OUT_DIM + col] : 0.f;
        __bf16 wh = (__bf16)w;
        bhi[i] = wh;
        blo[i] = (__bf16)(w - (float)wh);
      }
      acc[t] = __builtin_amdgcn_mfma_f32_16x16x32_bf16(av[c], bhi, acc[t], 0, 0, 0);
      acc[t] = __builtin_amdgcn_mfma_f32_16x16x32_bf16(av[c], blo, acc[t], 0, 0, 0);
    }
  }

  int rowbase = blockIdx.x * 64 + wave * 16 + kgrp * 4;
  #pragma unroll
  for (int r = 0; r < 4; ++r) {
    int row = rowbase + r;
    bool ok = row < n;
    float ps = 0.f, pd = 0.f;
    #pragma unroll
    for (int t = 0; t < 3; ++t) {
      int col = t * 16 + l15;
      if (col < OUT_DIM) {
        float v = acc[t][r];
        if (ok) xp2b[(size_t)row * OUT_DIM + col] = (__bf16)v;
        ps = fmaf(v, a_s2[col], ps);
        pd = fmaf(v, a_d2[col], pd);
      }
    }
    #pragma unroll
    for (int o = 1; o < 16; o <<= 1) {
      ps += __shfl_xor(ps, o, 16);
      pd += __shfl_xor(pd, o, 16);
    }
    if (ok && l15 == 0) { es2[row] = ps; ed2[row] = pd; }
  }
}

// ---------------- layer 2 aggregation: pair-vectorized two-phase softmax ----------------
__global__ __launch_bounds__(256) void agg2_csr(
    const int* __restrict__ offs, const int* __restrict__ srcs,
    const float* __restrict__ es2, const float* __restrict__ ed2,
    const __bf16* __restrict__ xp2b, const float* __restrict__ b2,
    float* __restrict__ out, int n) {
  __shared__ float lds[4][64 * 2];
  int wave = threadIdx.x >> 6;
  int wid = (blockIdx.x * 256 + threadIdx.x) >> 6;
  if (wid >= n) return;
  int lane = threadIdx.x & 63;
  int a = lane & 31, half = lane >> 5;
  int ch0 = a * 2;                        // valid when a < 20
  int beg = offs[wid], end = offs[wid + 1];
  float edv = ed2[wid];
  float zacc = 0.f, acc0 = 0.f, acc1 = 0.f;
  const char* xbase = (const char*)xp2b + ch0 * 2;
  float* myl = lds[wave];

  for (int e0 = beg; e0 < end; e0 += 64) {
    int cnt = min(64, end - e0);
    float ex = 0.f;
    int s = 0;
    if (lane < cnt) {
      s = srcs[e0 + lane];
      ex = __expf(lrelu(es2[s] + edv));
    }
    zacc += ex;
    myl[lane * 2]     = ex;
    myl[lane * 2 + 1] = __int_as_float(s * (int)(OUT_DIM * sizeof(__bf16)));
    if (a < 20) {
      int jpmax = (cnt + 1 - half) >> 1;
      int jp = 0;
      for (; jp + 8 <= jpmax; jp += 8) {
        float2 ao[8];
        #pragma unroll
        for (int k = 0; k < 8; ++k)
          ao[k] = *(const float2*)&myl[((jp + k) * 2 + half) * 2];
        unsigned wj[8];
        #pragma unroll
        for (int k = 0; k < 8; ++k)
          wj[k] = *(const unsigned*)(xbase + __float_as_int(ao[k].y));
        #pragma unroll
        for (int k = 0; k < 8; ++k) {
          float f0 = __int_as_float((int)(wj[k] << 16));
          float f1 = __int_as_float((int)(wj[k] & 0xffff0000u));
          acc0 = fmaf(ao[k].x, f0, acc0);
          acc1 = fmaf(ao[k].x, f1, acc1);
        }
      }
      #pragma unroll 4
      for (; jp < jpmax; ++jp) {
        float2 ao = *(const float2*)&myl[(jp * 2 + half) * 2];
        unsigned w = *(const unsigned*)(xbase + __float_as_int(ao.y));
        float f0 = __int_as_float((int)(w << 16));
        float f1 = __int_as_float((int)(w & 0xffff0000u));
        acc0 = fmaf(ao.x, f0, acc0);
        acc1 = fmaf(ao.x, f1, acc1);
      }
    }
  }

  float z = zacc;
  #pragma unroll
  for (int o = 1; o < 64; o <<= 1) z += __shfl_xor(z, o);
  acc0 += __shfl_xor(acc0, 32);
  acc1 += __shfl_xor(acc1, 32);
  if (half == 0 && a < 20) {
    float inv = 1.f / (z + 1e-16f);
    float2 r;
    r.x = fmaf(acc0, inv, b2[ch0]);
    r.y = fmaf(acc1, inv, b2[ch0 + 1]);
    *(float2*)&out[(size_t)wid * OUT_DIM + ch0] = r;
  }
}

extern "C" void kernel_launch(void* const* d_in, const int* in_sizes, int n_in,
                              void* d_out, int out_size, void* d_ws, size_t ws_size,
                              hipStream_t stream) {
  const float* x    = (const float*)d_in[0];
  const int*   ei   = (const int*)d_in[1];
  const float* W1   = (const float*)d_in[2];
  const float* a_s1 = (const float*)d_in[3];
  const float* a_d1 = (const float*)d_in[4];
  const float* b1   = (const float*)d_in[5];
  const float* W2   = (const float*)d_in[6];
  const float* a_s2 = (const float*)d_in[7];
  const float* a_d2 = (const float*)d_in[8];
  const float* b2   = (const float*)d_in[9];

  int n  = in_sizes[0] / IN_DIM;
  int E  = in_sizes[1] / 2;
  int ET = E + n;
  int nbuck = (n + 255) >> NB_SH;
  int nblk1 = (ET + CHUNK - 1) / CHUNK;
  int ntile = (n + 127) / 128;
  int t0 = ntile / 2;
  float* out = (float*)d_out;

  char* ws = (char*)d_ws;
  size_t off = 0;
  auto alloc = [&](size_t bytes) -> void* {
    void* p = ws + off;
    off = (off + bytes + 255) & ~(size_t)255;
    return p;
  };
  __bf16* xp1b     = (__bf16*)alloc((size_t)n * HC * 2);
  __bf16* xp2b     = (__bf16*)alloc((size_t)n * OUT_DIM * 2);
  __bf16* hb       = (__bf16*)alloc((size_t)n * HC * 2);
  float*  es1      = (float*)alloc((size_t)n * 4 * 4);
  float*  ed1      = (float*)alloc((size_t)n * 4 * 4);
  float*  es2      = (float*)alloc((size_t)n * 4);
  float*  ed2      = (float*)alloc((size_t)n * 4);
  int*    blkhistT = (int*)alloc((size_t)nblk1 * nbuck * 4);
  int*    cur      = (int*)alloc((size_t)nblk1 * nbuck * 4);
  int*    btot     = (int*)alloc((size_t)(nbuck + 1) * 4);
  int*    bstart   = (int*)alloc((size_t)(nbuck + 1) * 4);
  int*    offs     = (int*)alloc((size_t)(n + 1) * 4);
  int*    srcs     = (int*)alloc((size_t)ET * 4);
  unsigned int* pairs = (unsigned int*)alloc((size_t)ET * 4);
  __bf16* Wt       = (__bf16*)alloc((size_t)IN_DIM * HC * 2);

  wprep_kernel<<<(IN_DIM * HC + 255) / 256, 256, 0, stream>>>(W1, Wt, btot, nbuck);
  hist_kernel<<<nblk1, 256, 0, stream>>>(ei, blkhistT, btot, E, ET, nbuck, nblk1);
  bscan_kernel<<<1, 512, 0, stream>>>(btot, bstart, offs, nbuck, ET, n);
  curs_kernel<<<nbuck, 256, 0, stream>>>(blkhistT, bstart, cur, nblk1, nbuck);
  fused_sg<<<nblk1 + t0, 512, 0, stream>>>(ei, cur, pairs, E, ET, nbuck, nblk1,
                                           x, Wt, a_s1, a_d1, xp1b, es1, ed1, n);
  fused_pg<<<nbuck + (ntile - t0), 512, 0, stream>>>(pairs, bstart, offs, srcs, n, nbuck, t0,
                                                     x, Wt, a_s1, a_d1, xp1b, es1, ed1);
  agg1_csr<<<(n * 64 + 255) / 256, 256, 0, stream>>>(offs, srcs, es1, ed1, xp1b, b1, hb, n);
  layer2_mfma<<<(n + 63) / 64, 256, 0, stream>>>(hb, W2, a_s2, a_d2, xp2b, es2, ed2, n);
  agg2_csr<<<(n * 64 + 255) / 256, 256, 0, stream>>>(offs, srcs, es2, ed2, xp2b, b2, out, n);
}